// Round 17
// baseline (191.819 us; speedup 1.0000x reference)
//
#include <hip/hip_runtime.h>
#include <hip/hip_bf16.h>
#include <hip/hip_fp16.h>
#include <stdint.h>

#define NF 64
#define NC 40
#define ZROW 64        // padded z row: 64 halves = 128 B
#define ELLCAP 64      // neighbor slots per node (max deg ~38 for Poisson 12.5)

typedef _Float16 f16x8 __attribute__((ext_vector_type(8)));
typedef float f32x4 __attribute__((ext_vector_type(4)));

__device__ __forceinline__ long long load_idx(const void* p, long long i, int is32) {
    if (is32) return (long long)((const int*)p)[i];
    return ((const long long*)p)[i];
}

// ---------------------------------------------------------------------------
// Fused init: block 0 detects edge dtype (int64 -> odd 32-bit words all zero);
// remaining blocks zero the degree counters.
// ---------------------------------------------------------------------------
__global__ void init_kernel(const unsigned int* __restrict__ p, int* __restrict__ flag,
                            int n_check, int* __restrict__ cnt, int N) {
    if (blockIdx.x == 0) {
        __shared__ int s_any;
        if (threadIdx.x == 0) s_any = 0;
        __syncthreads();
        int any = 0;
        for (int i = threadIdx.x; i < n_check; i += blockDim.x) {
            if (p[2 * i + 1] != 0u) any = 1;
        }
        if (any) atomicOr(&s_any, 1);
        __syncthreads();
        if (threadIdx.x == 0) *flag = s_any;
        return;
    }
    int i = (blockIdx.x - 1) * blockDim.x + threadIdx.x;
    if (i < N) cnt[i] = 0;
}

// cnt[col[e]] += 1; epos[e] = slot (atomic return value).
__global__ void count_kernel(const void* __restrict__ ei, int* __restrict__ cnt,
                             int* __restrict__ epos, const int* __restrict__ flag, long long E) {
    long long e = (long long)blockIdx.x * blockDim.x + threadIdx.x;
    if (e >= E) return;
    int is32 = *flag;
    int c = (int)load_idx(ei, E + e, is32);
    epos[e] = atomicAdd(&cnt[c], 1);
}

// ---------------------------------------------------------------------------
// Fused: ELL scatter || zgemm (MFMA), block types INTERLEAVED (every 4th block
// is zgemm) so both are co-resident -> MFMA work hides under the scatter's
// latency-bound waves (m114: co-resident different-pipe waves run at max).
// Both types depend only on count's outputs (cnt, epos).
// zgemm: z[i][c] = half( rsqrt(1+cnt[i]) * sum_f x[i][f]*W[c][f] ), 16 nodes/wave.
// ---------------------------------------------------------------------------
__global__ void fill_zgemm_kernel(const void* __restrict__ ei, const int* __restrict__ epos,
                                  int* __restrict__ ell, const int* __restrict__ flag,
                                  const float* __restrict__ x, const float* __restrict__ W,
                                  const int* __restrict__ cnt, __half* __restrict__ z,
                                  int N, long long E, int nZ) {
    int bid = blockIdx.x;
    bool isZ = ((bid & 3) == 3) && ((bid >> 2) < nZ);

    if (!isZ) {
        // ---- ELL scatter: ell[c*ELLCAP + epos[e]] = r (no atomics) ----
        int nzBefore = (bid + 1) >> 2;
        if (nzBefore > nZ) nzBefore = nZ;
        int fi = bid - nzBefore;
        long long e = (long long)fi * blockDim.x + threadIdx.x;
        if (e >= E) return;
        int is32 = *flag;
        int r = (int)load_idx(ei, e, is32);
        int c = (int)load_idx(ei, E + e, is32);
        int pos = epos[e];
        if (pos < ELLCAP) ell[(size_t)c * ELLCAP + pos] = r;
        return;
    }

    // ---- zgemm tile: one wave = 16 nodes x 48 classes (3 MFMA class-tiles) ----
    int zi = bid >> 2;
    int lane = threadIdx.x & 63;
    int wid = (zi << 2) + ((threadIdx.x >> 6) & 3);
    int base = wid * 16;
    if (base >= N) return;

    int lrow = lane & 15;  // A row-in-tile / B class col / D class col
    int lk = lane >> 4;    // k-group (8 consecutive k each)

    f16x8 bfrag[3][2];
#pragma unroll
    for (int ct = 0; ct < 3; ++ct) {
        int wrow = ct * 16 + lrow;
        if (wrow > NC - 1) wrow = NC - 1;  // clamp pad classes (never stored)
        const float* wp = W + (size_t)wrow * NF;
#pragma unroll
        for (int kk = 0; kk < 2; ++kk) {
            float4 wa = *(const float4*)(wp + kk * 32 + lk * 8);
            float4 wb = *(const float4*)(wp + kk * 32 + lk * 8 + 4);
            f16x8 t;
            t[0] = (_Float16)wa.x; t[1] = (_Float16)wa.y;
            t[2] = (_Float16)wa.z; t[3] = (_Float16)wa.w;
            t[4] = (_Float16)wb.x; t[5] = (_Float16)wb.y;
            t[6] = (_Float16)wb.z; t[7] = (_Float16)wb.w;
            bfrag[ct][kk] = t;
        }
    }

    int arow = base + lrow;
    if (arow > N - 1) arow = N - 1;
    const float* xp = x + (size_t)arow * NF;
    f16x8 afrag[2];
#pragma unroll
    for (int kk = 0; kk < 2; ++kk) {
        float4 xa = *(const float4*)(xp + kk * 32 + lk * 8);
        float4 xb = *(const float4*)(xp + kk * 32 + lk * 8 + 4);
        f16x8 t;
        t[0] = (_Float16)xa.x; t[1] = (_Float16)xa.y;
        t[2] = (_Float16)xa.z; t[3] = (_Float16)xa.w;
        t[4] = (_Float16)xb.x; t[5] = (_Float16)xb.y;
        t[6] = (_Float16)xb.z; t[7] = (_Float16)xb.w;
        afrag[kk] = t;
    }

    f32x4 acc0 = {0.f, 0.f, 0.f, 0.f};
    f32x4 acc1 = {0.f, 0.f, 0.f, 0.f};
    f32x4 acc2 = {0.f, 0.f, 0.f, 0.f};
    acc0 = __builtin_amdgcn_mfma_f32_16x16x32_f16(afrag[0], bfrag[0][0], acc0, 0, 0, 0);
    acc0 = __builtin_amdgcn_mfma_f32_16x16x32_f16(afrag[1], bfrag[0][1], acc0, 0, 0, 0);
    acc1 = __builtin_amdgcn_mfma_f32_16x16x32_f16(afrag[0], bfrag[1][0], acc1, 0, 0, 0);
    acc1 = __builtin_amdgcn_mfma_f32_16x16x32_f16(afrag[1], bfrag[1][1], acc1, 0, 0, 0);
    acc2 = __builtin_amdgcn_mfma_f32_16x16x32_f16(afrag[0], bfrag[2][0], acc2, 0, 0, 0);
    acc2 = __builtin_amdgcn_mfma_f32_16x16x32_f16(afrag[1], bfrag[2][1], acc2, 0, 0, 0);

    // dinv computed inline from degree counters (no dinv array)
    int4 cv = *(const int4*)(cnt + base + lk * 4);

    // C/D mapping (m89-verified): col = lane&15, row = (lane>>4)*4 + reg.
#pragma unroll
    for (int r = 0; r < 4; ++r) {
        int row = base + lk * 4 + r;
        if (row >= N) break;
        int cdeg = (r == 0) ? cv.x : (r == 1) ? cv.y : (r == 2) ? cv.z : cv.w;
        float d = rsqrtf(1.0f + (float)cdeg);
        __half* zr = z + (size_t)row * ZROW;
        zr[lrow] = __float2half(d * acc0[r]);                     // classes 0..15
        zr[16 + lrow] = __float2half(d * acc1[r]);                // classes 16..31
        if (lrow < 8) zr[32 + lrow] = __float2half(d * acc2[r]);  // classes 32..39
    }
}

// ---------------------------------------------------------------------------
// Hop kernels: 8 nodes per wave (8 groups x 8 lanes). Lane jg of group g holds
// classes [8jg..8jg+7] of node (wave*8+g). One gather instruction = 8 full
// 128B rows. ELL slots preloaded as int4; intra-group shfl broadcast (branch
// cond is group-uniform -> shfl sources always active). fp32 accumulate.
// ---------------------------------------------------------------------------
__device__ __forceinline__ void add_row(float2 (&acc)[4], float4 raw) {
    union { float4 f; __half2 h[4]; } u;
    u.f = raw;
#pragma unroll
    for (int q = 0; q < 4; ++q) {
        float2 t = __half22float2(u.h[q]);
        acc[q].x += t.x;
        acc[q].y += t.y;
    }
}

__device__ __forceinline__ void gather_rows(float2 (&acc)[4], const float4* __restrict__ vp,
                                            const int* __restrict__ ell_row, int deg, int wmax,
                                            int base, int jg) {
    const int4* ep = (const int4*)ell_row;
    int4 ia = ep[jg];  // slots 4jg..4jg+3
#pragma unroll
    for (int r = 0; r < 4; ++r) {
        int ir = (r == 0) ? ia.x : (r == 1) ? ia.y : (r == 2) ? ia.z : ia.w;
#pragma unroll
        for (int j = 0; j < 8; ++j) {
            if (4 * j + r < deg) {  // group-uniform
                int s = __shfl(ir, base + j);
                add_row(acc, vp[(size_t)s * 8 + jg]);
            }
        }
    }
    if (wmax > 32) {  // wave-uniform; essentially never taken
        int4 ib = ep[8 + jg];  // slots 32+4jg..
#pragma unroll
        for (int r = 0; r < 4; ++r) {
            int ir = (r == 0) ? ib.x : (r == 1) ? ib.y : (r == 2) ? ib.z : ib.w;
#pragma unroll
            for (int j = 0; j < 8; ++j) {
                if (32 + 4 * j + r < deg) {
                    int s = __shfl(ir, base + j);
                    add_row(acc, vp[(size_t)s * 8 + jg]);
                }
            }
        }
    }
}

__global__ void hop_kernel(const __half* __restrict__ vin, __half* __restrict__ vout,
                           const int* __restrict__ cnt, const int* __restrict__ ell, int N) {
    int lane = threadIdx.x & 63;
    int g = lane >> 3, jg = lane & 7;
    int wave = (int)(((long long)blockIdx.x * blockDim.x + threadIdx.x) >> 6);
    int node = wave * 8 + g;
    bool valid = node < N;
    int nc = valid ? node : N - 1;

    int rawdeg = cnt[nc];
    float d = rsqrtf(1.0f + (float)rawdeg);
    int deg = (rawdeg > ELLCAP) ? ELLCAP : rawdeg;
    int wmax = deg;
    wmax = max(wmax, __shfl_xor(wmax, 8));
    wmax = max(wmax, __shfl_xor(wmax, 16));
    wmax = max(wmax, __shfl_xor(wmax, 32));

    const float4* vp = (const float4*)vin;
    float2 acc[4];
#pragma unroll
    for (int q = 0; q < 4; ++q) acc[q] = make_float2(0.f, 0.f);
    add_row(acc, vp[(size_t)nc * 8 + jg]);  // self term

    gather_rows(acc, vp, ell + (size_t)nc * ELLCAP, deg, wmax, lane & 56, jg);

    if (valid) {
        float d2 = d * d;
        union { float4 f; __half2 h[4]; } o;
#pragma unroll
        for (int q = 0; q < 4; ++q)
            o.h[q] = __float22half2_rn(make_float2(d2 * acc[q].x, d2 * acc[q].y));
        ((float4*)vout)[(size_t)node * 8 + jg] = o.f;
    }
}

__global__ void hop_final_kernel(const __half* __restrict__ vin, const float* __restrict__ b,
                                 float* __restrict__ out, const int* __restrict__ cnt,
                                 const int* __restrict__ ell, int N) {
    int lane = threadIdx.x & 63;
    int g = lane >> 3, jg = lane & 7;
    int wave = (int)(((long long)blockIdx.x * blockDim.x + threadIdx.x) >> 6);
    int node = wave * 8 + g;
    bool valid = node < N;
    int nc = valid ? node : N - 1;

    int rawdeg = cnt[nc];
    float d = rsqrtf(1.0f + (float)rawdeg);
    int deg = (rawdeg > ELLCAP) ? ELLCAP : rawdeg;
    int wmax = deg;
    wmax = max(wmax, __shfl_xor(wmax, 8));
    wmax = max(wmax, __shfl_xor(wmax, 16));
    wmax = max(wmax, __shfl_xor(wmax, 32));

    const float4* vp = (const float4*)vin;
    float2 acc[4];
#pragma unroll
    for (int q = 0; q < 4; ++q) acc[q] = make_float2(0.f, 0.f);
    add_row(acc, vp[(size_t)nc * 8 + jg]);  // self term

    gather_rows(acc, vp, ell + (size_t)nc * ELLCAP, deg, wmax, lane & 56, jg);

    float2 bv[4];
#pragma unroll
    for (int q = 0; q < 4; ++q) bv[q] = make_float2(0.f, 0.f);
    if (jg < 5) {
        float4 b0 = ((const float4*)b)[2 * jg];
        float4 b1 = ((const float4*)b)[2 * jg + 1];
        bv[0] = make_float2(b0.x, b0.y);
        bv[1] = make_float2(b0.z, b0.w);
        bv[2] = make_float2(b1.x, b1.y);
        bv[3] = make_float2(b1.z, b1.w);
    }

    float2 l[4];
#pragma unroll
    for (int q = 0; q < 4; ++q) {
        l[q].x = fmaxf(d * acc[q].x + bv[q].x, 0.0f);
        l[q].y = fmaxf(d * acc[q].y + bv[q].y, 0.0f);
        if (jg >= 5) l[q] = make_float2(0.f, 0.f);  // mask pad classes
    }

    // group-local max (real logits >= 0, pads hold 0 -> harmless)
    float mx = 0.0f;
#pragma unroll
    for (int q = 0; q < 4; ++q) mx = fmaxf(mx, fmaxf(l[q].x, l[q].y));
    mx = fmaxf(mx, __shfl_xor(mx, 1));
    mx = fmaxf(mx, __shfl_xor(mx, 2));
    mx = fmaxf(mx, __shfl_xor(mx, 4));

    float e = 0.0f;
    if (jg < 5) {
#pragma unroll
        for (int q = 0; q < 4; ++q) e += __expf(l[q].x - mx) + __expf(l[q].y - mx);
    }
    e += __shfl_xor(e, 1);
    e += __shfl_xor(e, 2);
    e += __shfl_xor(e, 4);
    float lse = mx + __logf(e);

    if (valid && jg < 5) {
        float4 o0 = make_float4(l[0].x - lse, l[0].y - lse, l[1].x - lse, l[1].y - lse);
        float4 o1 = make_float4(l[2].x - lse, l[2].y - lse, l[3].x - lse, l[3].y - lse);
        float4* op = (float4*)out + (size_t)node * 10 + 2 * jg;
        op[0] = o0;
        op[1] = o1;
    }
}

extern "C" void kernel_launch(void* const* d_in, const int* in_sizes, int n_in,
                              void* d_out, int out_size, void* d_ws, size_t ws_size,
                              hipStream_t stream) {
    const float* x = (const float*)d_in[0];
    const void* ei = d_in[1];
    const float* W = (const float*)d_in[2];
    const float* b = (const float*)d_in[3];
    float* out = (float*)d_out;

    const int N = in_sizes[0] / NF;          // 100000
    const long long E = in_sizes[1] / 2;     // 1250000

    // workspace layout (256B aligned chunks)
    size_t off = 0;
    int* flag = (int*)((char*)d_ws + off);
    off += 256;
    int* cnt = (int*)((char*)d_ws + off);
    off += ((size_t)N * 4 + 255) & ~(size_t)255;
    int* epos = (int*)((char*)d_ws + off);
    off += ((size_t)E * 4 + 255) & ~(size_t)255;
    int* ell = (int*)((char*)d_ws + off);
    off += ((size_t)N * ELLCAP * 4 + 255) & ~(size_t)255;   // 25.6 MB
    __half* z1 = (__half*)((char*)d_ws + off);
    size_t z_bytes = (size_t)N * ZROW * 2;
    off += (z_bytes + 255) & ~(size_t)255;
    __half* z2 = (__half*)((char*)d_ws + off);
    off += (z_bytes + 255) & ~(size_t)255;
    if (off > ws_size) return;

    const int B = 256;
    int gridN = (N + B - 1) / B;                            // 391
    int gridE = (int)((E + B - 1) / B);                     // 4883
    long long hopThreads = (((long long)N + 7) / 8) * 64;   // 8 nodes per wave
    int gridH = (int)((hopThreads + B - 1) / B);

    // 0. init: detect dtype (block 0) + zero degree counters
    int n_check = (int)((E < 4096) ? E : 4096);
    init_kernel<<<1 + gridN, B, 0, stream>>>((const unsigned int*)ei, flag, n_check, cnt, N);

    // 1. count degrees + record slots
    count_kernel<<<gridE, B, 0, stream>>>(ei, cnt, epos, flag, E);

    // 2. fused: ELL scatter || zgemm (interleaved every 4th block)
    int nZ = ((N + 63) / 64);                               // 1563 zgemm blocks
    int totalBlocks = gridE + nZ;
    fill_zgemm_kernel<<<totalBlocks, B, 0, stream>>>(ei, epos, ell, flag, x, W, cnt, z1, N, E, nZ);

    // 3. hops 1,2 (fp16, 8 nodes/wave); hop 3 fused with bias+relu+log_softmax
    hop_kernel<<<gridH, B, 0, stream>>>(z1, z2, cnt, ell, N);
    hop_kernel<<<gridH, B, 0, stream>>>(z2, z1, cnt, ell, N);
    hop_final_kernel<<<gridH, B, 0, stream>>>(z1, b, out, cnt, ell, N);
}

// Round 18
// 169.417 us; speedup vs baseline: 1.1322x; 1.1322x over previous
//
#include <hip/hip_runtime.h>
#include <hip/hip_bf16.h>
#include <hip/hip_fp16.h>
#include <stdint.h>

#define NF 64
#define NC 40
#define ZROW 64        // padded z row: 64 halves = 128 B
#define ELLCAP 64      // neighbor slots per node (max deg ~38 for Poisson 12.5)

typedef _Float16 f16x8 __attribute__((ext_vector_type(8)));
typedef float f32x4 __attribute__((ext_vector_type(4)));

__device__ __forceinline__ long long load_idx(const void* p, long long i, int is32) {
    if (is32) return (long long)((const int*)p)[i];
    return ((const long long*)p)[i];
}

// ---------------------------------------------------------------------------
// Fused init: block 0 detects edge dtype (int64 -> odd 32-bit words all zero);
// remaining blocks zero the degree counters.
// ---------------------------------------------------------------------------
__global__ void init_kernel(const unsigned int* __restrict__ p, int* __restrict__ flag,
                            int n_check, int* __restrict__ cnt, int N) {
    if (blockIdx.x == 0) {
        __shared__ int s_any;
        if (threadIdx.x == 0) s_any = 0;
        __syncthreads();
        int any = 0;
        for (int i = threadIdx.x; i < n_check; i += blockDim.x) {
            if (p[2 * i + 1] != 0u) any = 1;
        }
        if (any) atomicOr(&s_any, 1);
        __syncthreads();
        if (threadIdx.x == 0) *flag = s_any;
        return;
    }
    int i = (blockIdx.x - 1) * blockDim.x + threadIdx.x;
    if (i < N) cnt[i] = 0;
}

// ---------------------------------------------------------------------------
// Fused: degree count (atomic-op-rate bound, ~0.8 TB/s write-through, VALU and
// MFMA idle) || zgemm_raw (MFMA + streaming reads). Block types interleaved
// (every 4th block is zgemm) so both are co-resident. zgemm computes z_raw =
// x W^T UNSCALED -> no dependency on cnt -> can legally overlap with count.
// The D^{-1/2} right-scaling moves into hop1's gather (d_s per source).
// ---------------------------------------------------------------------------
__global__ void count_zgemm_kernel(const void* __restrict__ ei, int* __restrict__ cnt,
                                   int* __restrict__ epos, const int* __restrict__ flag,
                                   const float* __restrict__ x, const float* __restrict__ W,
                                   __half* __restrict__ z, int N, long long E, int nZ) {
    int bid = blockIdx.x;
    bool isZ = ((bid & 3) == 3) && ((bid >> 2) < nZ);

    if (!isZ) {
        // ---- count: epos[e] = atomicAdd(&cnt[c], 1) ----
        int nzBefore = (bid + 1) >> 2;
        if (nzBefore > nZ) nzBefore = nZ;
        int fi = bid - nzBefore;
        long long e = (long long)fi * blockDim.x + threadIdx.x;
        if (e >= E) return;
        int is32 = *flag;
        int c = (int)load_idx(ei, E + e, is32);
        epos[e] = atomicAdd(&cnt[c], 1);
        return;
    }

    // ---- zgemm_raw tile: one wave = 16 nodes x 48 classes (3 MFMA tiles) ----
    int zi = bid >> 2;
    int lane = threadIdx.x & 63;
    int wid = (zi << 2) + ((threadIdx.x >> 6) & 3);
    int base = wid * 16;
    if (base >= N) return;

    int lrow = lane & 15;  // A row-in-tile / B class col / D class col
    int lk = lane >> 4;    // k-group (8 consecutive k each)

    f16x8 bfrag[3][2];
#pragma unroll
    for (int ct = 0; ct < 3; ++ct) {
        int wrow = ct * 16 + lrow;
        if (wrow > NC - 1) wrow = NC - 1;  // clamp pad classes (never stored)
        const float* wp = W + (size_t)wrow * NF;
#pragma unroll
        for (int kk = 0; kk < 2; ++kk) {
            float4 wa = *(const float4*)(wp + kk * 32 + lk * 8);
            float4 wb = *(const float4*)(wp + kk * 32 + lk * 8 + 4);
            f16x8 t;
            t[0] = (_Float16)wa.x; t[1] = (_Float16)wa.y;
            t[2] = (_Float16)wa.z; t[3] = (_Float16)wa.w;
            t[4] = (_Float16)wb.x; t[5] = (_Float16)wb.y;
            t[6] = (_Float16)wb.z; t[7] = (_Float16)wb.w;
            bfrag[ct][kk] = t;
        }
    }

    int arow = base + lrow;
    if (arow > N - 1) arow = N - 1;
    const float* xp = x + (size_t)arow * NF;
    f16x8 afrag[2];
#pragma unroll
    for (int kk = 0; kk < 2; ++kk) {
        float4 xa = *(const float4*)(xp + kk * 32 + lk * 8);
        float4 xb = *(const float4*)(xp + kk * 32 + lk * 8 + 4);
        f16x8 t;
        t[0] = (_Float16)xa.x; t[1] = (_Float16)xa.y;
        t[2] = (_Float16)xa.z; t[3] = (_Float16)xa.w;
        t[4] = (_Float16)xb.x; t[5] = (_Float16)xb.y;
        t[6] = (_Float16)xb.z; t[7] = (_Float16)xb.w;
        afrag[kk] = t;
    }

    f32x4 acc0 = {0.f, 0.f, 0.f, 0.f};
    f32x4 acc1 = {0.f, 0.f, 0.f, 0.f};
    f32x4 acc2 = {0.f, 0.f, 0.f, 0.f};
    acc0 = __builtin_amdgcn_mfma_f32_16x16x32_f16(afrag[0], bfrag[0][0], acc0, 0, 0, 0);
    acc0 = __builtin_amdgcn_mfma_f32_16x16x32_f16(afrag[1], bfrag[0][1], acc0, 0, 0, 0);
    acc1 = __builtin_amdgcn_mfma_f32_16x16x32_f16(afrag[0], bfrag[1][0], acc1, 0, 0, 0);
    acc1 = __builtin_amdgcn_mfma_f32_16x16x32_f16(afrag[1], bfrag[1][1], acc1, 0, 0, 0);
    acc2 = __builtin_amdgcn_mfma_f32_16x16x32_f16(afrag[0], bfrag[2][0], acc2, 0, 0, 0);
    acc2 = __builtin_amdgcn_mfma_f32_16x16x32_f16(afrag[1], bfrag[2][1], acc2, 0, 0, 0);

    // C/D mapping (m89-verified): col = lane&15, row = (lane>>4)*4 + reg.
#pragma unroll
    for (int r = 0; r < 4; ++r) {
        int row = base + lk * 4 + r;
        if (row >= N) break;
        __half* zr = z + (size_t)row * ZROW;
        zr[lrow] = __float2half(acc0[r]);                     // classes 0..15
        zr[16 + lrow] = __float2half(acc1[r]);                // classes 16..31
        if (lrow < 8) zr[32 + lrow] = __float2half(acc2[r]);  // classes 32..39
    }
}

// ell[c*ELLCAP + epos[e]] = r   (pure scatter, no atomics)
__global__ void fill_kernel(const void* __restrict__ ei, const int* __restrict__ epos,
                            int* __restrict__ ell, const int* __restrict__ flag, long long E) {
    long long e = (long long)blockIdx.x * blockDim.x + threadIdx.x;
    if (e >= E) return;
    int is32 = *flag;
    int r = (int)load_idx(ei, e, is32);
    int c = (int)load_idx(ei, E + e, is32);
    int pos = epos[e];
    if (pos < ELLCAP) ell[(size_t)c * ELLCAP + pos] = r;
}

// ---------------------------------------------------------------------------
// Hop kernels: 8 nodes per wave (8 groups x 8 lanes). Lane jg of group g holds
// classes [8jg..8jg+7] of node (wave*8+g). One gather instruction = 8 full
// 128B rows. ELL slots preloaded as int4; intra-group shfl broadcast (branch
// cond is group-uniform -> shfl sources always active). fp32 accumulate.
// ---------------------------------------------------------------------------
__device__ __forceinline__ void add_row(float2 (&acc)[4], float4 raw) {
    union { float4 f; __half2 h[4]; } u;
    u.f = raw;
#pragma unroll
    for (int q = 0; q < 4; ++q) {
        float2 t = __half22float2(u.h[q]);
        acc[q].x += t.x;
        acc[q].y += t.y;
    }
}

__device__ __forceinline__ void add_row_scaled(float2 (&acc)[4], float4 raw, float s) {
    union { float4 f; __half2 h[4]; } u;
    u.f = raw;
#pragma unroll
    for (int q = 0; q < 4; ++q) {
        float2 t = __half22float2(u.h[q]);
        acc[q].x += s * t.x;
        acc[q].y += s * t.y;
    }
}

__device__ __forceinline__ void gather_rows(float2 (&acc)[4], const float4* __restrict__ vp,
                                            const int* __restrict__ ell_row, int deg, int wmax,
                                            int base, int jg) {
    const int4* ep = (const int4*)ell_row;
    int4 ia = ep[jg];  // slots 4jg..4jg+3
#pragma unroll
    for (int r = 0; r < 4; ++r) {
        int ir = (r == 0) ? ia.x : (r == 1) ? ia.y : (r == 2) ? ia.z : ia.w;
#pragma unroll
        for (int j = 0; j < 8; ++j) {
            if (4 * j + r < deg) {  // group-uniform
                int s = __shfl(ir, base + j);
                add_row(acc, vp[(size_t)s * 8 + jg]);
            }
        }
    }
    if (wmax > 32) {  // wave-uniform; essentially never taken
        int4 ib = ep[8 + jg];
#pragma unroll
        for (int r = 0; r < 4; ++r) {
            int ir = (r == 0) ? ib.x : (r == 1) ? ib.y : (r == 2) ? ib.z : ib.w;
#pragma unroll
            for (int j = 0; j < 8; ++j) {
                if (32 + 4 * j + r < deg) {
                    int s = __shfl(ir, base + j);
                    add_row(acc, vp[(size_t)s * 8 + jg]);
                }
            }
        }
    }
}

// hop1 variant: each gathered row scaled by d_s = rsqrt(1+cnt[s]) (fp32).
__device__ __forceinline__ void gather_rows_dsrc(float2 (&acc)[4], const float4* __restrict__ vp,
                                                 const int* __restrict__ ell_row,
                                                 const int* __restrict__ cnt, int deg, int wmax,
                                                 int base, int jg) {
    const int4* ep = (const int4*)ell_row;
    int4 ia = ep[jg];
#pragma unroll
    for (int r = 0; r < 4; ++r) {
        int ir = (r == 0) ? ia.x : (r == 1) ? ia.y : (r == 2) ? ia.z : ia.w;
#pragma unroll
        for (int j = 0; j < 8; ++j) {
            if (4 * j + r < deg) {
                int s = __shfl(ir, base + j);
                float ds = rsqrtf(1.0f + (float)cnt[s]);  // L2-resident, same addr per group
                add_row_scaled(acc, vp[(size_t)s * 8 + jg], ds);
            }
        }
    }
    if (wmax > 32) {
        int4 ib = ep[8 + jg];
#pragma unroll
        for (int r = 0; r < 4; ++r) {
            int ir = (r == 0) ? ib.x : (r == 1) ? ib.y : (r == 2) ? ib.z : ib.w;
#pragma unroll
            for (int j = 0; j < 8; ++j) {
                if (32 + 4 * j + r < deg) {
                    int s = __shfl(ir, base + j);
                    float ds = rsqrtf(1.0f + (float)cnt[s]);
                    add_row_scaled(acc, vp[(size_t)s * 8 + jg], ds);
                }
            }
        }
    }
}

// hop1: v1[i] = d_i^2 * ( d_i * zraw[i] + sum_s d_s * zraw[s] )
__global__ void hop1_kernel(const __half* __restrict__ vin, __half* __restrict__ vout,
                            const int* __restrict__ cnt, const int* __restrict__ ell, int N) {
    int lane = threadIdx.x & 63;
    int g = lane >> 3, jg = lane & 7;
    int wave = (int)(((long long)blockIdx.x * blockDim.x + threadIdx.x) >> 6);
    int node = wave * 8 + g;
    bool valid = node < N;
    int nc = valid ? node : N - 1;

    int rawdeg = cnt[nc];
    float d = rsqrtf(1.0f + (float)rawdeg);
    int deg = (rawdeg > ELLCAP) ? ELLCAP : rawdeg;
    int wmax = deg;
    wmax = max(wmax, __shfl_xor(wmax, 8));
    wmax = max(wmax, __shfl_xor(wmax, 16));
    wmax = max(wmax, __shfl_xor(wmax, 32));

    const float4* vp = (const float4*)vin;
    float2 acc[4];
#pragma unroll
    for (int q = 0; q < 4; ++q) acc[q] = make_float2(0.f, 0.f);
    add_row_scaled(acc, vp[(size_t)nc * 8 + jg], d);  // self term: d_i * zraw[i]

    gather_rows_dsrc(acc, vp, ell + (size_t)nc * ELLCAP, cnt, deg, wmax, lane & 56, jg);

    if (valid) {
        float d2 = d * d;
        union { float4 f; __half2 h[4]; } o;
#pragma unroll
        for (int q = 0; q < 4; ++q)
            o.h[q] = __float22half2_rn(make_float2(d2 * acc[q].x, d2 * acc[q].y));
        ((float4*)vout)[(size_t)node * 8 + jg] = o.f;
    }
}

// hop2: v2[i] = d_i^2 * ( v1[i] + sum_s v1[s] )
__global__ void hop_kernel(const __half* __restrict__ vin, __half* __restrict__ vout,
                           const int* __restrict__ cnt, const int* __restrict__ ell, int N) {
    int lane = threadIdx.x & 63;
    int g = lane >> 3, jg = lane & 7;
    int wave = (int)(((long long)blockIdx.x * blockDim.x + threadIdx.x) >> 6);
    int node = wave * 8 + g;
    bool valid = node < N;
    int nc = valid ? node : N - 1;

    int rawdeg = cnt[nc];
    float d = rsqrtf(1.0f + (float)rawdeg);
    int deg = (rawdeg > ELLCAP) ? ELLCAP : rawdeg;
    int wmax = deg;
    wmax = max(wmax, __shfl_xor(wmax, 8));
    wmax = max(wmax, __shfl_xor(wmax, 16));
    wmax = max(wmax, __shfl_xor(wmax, 32));

    const float4* vp = (const float4*)vin;
    float2 acc[4];
#pragma unroll
    for (int q = 0; q < 4; ++q) acc[q] = make_float2(0.f, 0.f);
    add_row(acc, vp[(size_t)nc * 8 + jg]);  // self term

    gather_rows(acc, vp, ell + (size_t)nc * ELLCAP, deg, wmax, lane & 56, jg);

    if (valid) {
        float d2 = d * d;
        union { float4 f; __half2 h[4]; } o;
#pragma unroll
        for (int q = 0; q < 4; ++q)
            o.h[q] = __float22half2_rn(make_float2(d2 * acc[q].x, d2 * acc[q].y));
        ((float4*)vout)[(size_t)node * 8 + jg] = o.f;
    }
}

// hop3 fused with bias + relu + log_softmax; group-local reduction; coalesced
// 160B float4 row stores.
__global__ void hop_final_kernel(const __half* __restrict__ vin, const float* __restrict__ b,
                                 float* __restrict__ out, const int* __restrict__ cnt,
                                 const int* __restrict__ ell, int N) {
    int lane = threadIdx.x & 63;
    int g = lane >> 3, jg = lane & 7;
    int wave = (int)(((long long)blockIdx.x * blockDim.x + threadIdx.x) >> 6);
    int node = wave * 8 + g;
    bool valid = node < N;
    int nc = valid ? node : N - 1;

    int rawdeg = cnt[nc];
    float d = rsqrtf(1.0f + (float)rawdeg);
    int deg = (rawdeg > ELLCAP) ? ELLCAP : rawdeg;
    int wmax = deg;
    wmax = max(wmax, __shfl_xor(wmax, 8));
    wmax = max(wmax, __shfl_xor(wmax, 16));
    wmax = max(wmax, __shfl_xor(wmax, 32));

    const float4* vp = (const float4*)vin;
    float2 acc[4];
#pragma unroll
    for (int q = 0; q < 4; ++q) acc[q] = make_float2(0.f, 0.f);
    add_row(acc, vp[(size_t)nc * 8 + jg]);  // self term

    gather_rows(acc, vp, ell + (size_t)nc * ELLCAP, deg, wmax, lane & 56, jg);

    float2 bv[4];
#pragma unroll
    for (int q = 0; q < 4; ++q) bv[q] = make_float2(0.f, 0.f);
    if (jg < 5) {
        float4 b0 = ((const float4*)b)[2 * jg];
        float4 b1 = ((const float4*)b)[2 * jg + 1];
        bv[0] = make_float2(b0.x, b0.y);
        bv[1] = make_float2(b0.z, b0.w);
        bv[2] = make_float2(b1.x, b1.y);
        bv[3] = make_float2(b1.z, b1.w);
    }

    float2 l[4];
#pragma unroll
    for (int q = 0; q < 4; ++q) {
        l[q].x = fmaxf(d * acc[q].x + bv[q].x, 0.0f);
        l[q].y = fmaxf(d * acc[q].y + bv[q].y, 0.0f);
        if (jg >= 5) l[q] = make_float2(0.f, 0.f);  // mask pad classes
    }

    // group-local max (real logits >= 0, pads hold 0 -> harmless)
    float mx = 0.0f;
#pragma unroll
    for (int q = 0; q < 4; ++q) mx = fmaxf(mx, fmaxf(l[q].x, l[q].y));
    mx = fmaxf(mx, __shfl_xor(mx, 1));
    mx = fmaxf(mx, __shfl_xor(mx, 2));
    mx = fmaxf(mx, __shfl_xor(mx, 4));

    float e = 0.0f;
    if (jg < 5) {
#pragma unroll
        for (int q = 0; q < 4; ++q) e += __expf(l[q].x - mx) + __expf(l[q].y - mx);
    }
    e += __shfl_xor(e, 1);
    e += __shfl_xor(e, 2);
    e += __shfl_xor(e, 4);
    float lse = mx + __logf(e);

    if (valid && jg < 5) {
        float4 o0 = make_float4(l[0].x - lse, l[0].y - lse, l[1].x - lse, l[1].y - lse);
        float4 o1 = make_float4(l[2].x - lse, l[2].y - lse, l[3].x - lse, l[3].y - lse);
        float4* op = (float4*)out + (size_t)node * 10 + 2 * jg;
        op[0] = o0;
        op[1] = o1;
    }
}

extern "C" void kernel_launch(void* const* d_in, const int* in_sizes, int n_in,
                              void* d_out, int out_size, void* d_ws, size_t ws_size,
                              hipStream_t stream) {
    const float* x = (const float*)d_in[0];
    const void* ei = d_in[1];
    const float* W = (const float*)d_in[2];
    const float* b = (const float*)d_in[3];
    float* out = (float*)d_out;

    const int N = in_sizes[0] / NF;          // 100000
    const long long E = in_sizes[1] / 2;     // 1250000

    // workspace layout (256B aligned chunks)
    size_t off = 0;
    int* flag = (int*)((char*)d_ws + off);
    off += 256;
    int* cnt = (int*)((char*)d_ws + off);
    off += ((size_t)N * 4 + 255) & ~(size_t)255;
    int* epos = (int*)((char*)d_ws + off);
    off += ((size_t)E * 4 + 255) & ~(size_t)255;
    int* ell = (int*)((char*)d_ws + off);
    off += ((size_t)N * ELLCAP * 4 + 255) & ~(size_t)255;   // 25.6 MB
    __half* z1 = (__half*)((char*)d_ws + off);
    size_t z_bytes = (size_t)N * ZROW * 2;
    off += (z_bytes + 255) & ~(size_t)255;
    __half* z2 = (__half*)((char*)d_ws + off);
    off += (z_bytes + 255) & ~(size_t)255;
    if (off > ws_size) return;

    const int B = 256;
    int gridN = (N + B - 1) / B;                            // 391
    int gridE = (int)((E + B - 1) / B);                     // 4883
    long long hopThreads = (((long long)N + 7) / 8) * 64;   // 8 nodes per wave
    int gridH = (int)((hopThreads + B - 1) / B);

    // 0. init: detect dtype (block 0) + zero degree counters
    int n_check = (int)((E < 4096) ? E : 4096);
    init_kernel<<<1 + gridN, B, 0, stream>>>((const unsigned int*)ei, flag, n_check, cnt, N);

    // 1. fused: degree count (atomic-rate bound) || zgemm_raw (MFMA), interleaved.
    int nZ = ((N + 63) / 64);                               // 1563 zgemm blocks
    count_zgemm_kernel<<<gridE + nZ, B, 0, stream>>>(ei, cnt, epos, flag, x, W, z1, N, E, nZ);

    // 2. ELL scatter (pure, no atomics)
    fill_kernel<<<gridE, B, 0, stream>>>(ei, epos, ell, flag, E);

    // 3. hop1 applies d_s per source (folded D^{-1/2}); hops 2,3 as before
    hop1_kernel<<<gridH, B, 0, stream>>>(z1, z2, cnt, ell, N);
    hop_kernel<<<gridH, B, 0, stream>>>(z2, z1, cnt, ell, N);
    hop_final_kernel<<<gridH, B, 0, stream>>>(z1, b, out, cnt, ell, N);
}